// Round 6
// baseline (1208.920 us; speedup 1.0000x reference)
//
#include <hip/hip_runtime.h>
#include <stdint.h>

#define GM 4096   // 2*2048 rows of x
#define GN 8192   // out_features
#define GK 2048   // in_features

typedef float f32x4 __attribute__((ext_vector_type(4)));
typedef __bf16 bf16x8 __attribute__((ext_vector_type(8)));

__device__ __constant__ float NF4_LUT[16] = {
    -1.0f, -0.6961928009986877f, -0.5250730514526367f, -0.39491748809814453f,
    -0.28444138169288635f, -0.18477343022823334f, -0.09105003625154495f, 0.0f,
    0.07958029955625534f, 0.16093020141124725f, 0.24611230194568634f,
    0.33791524171829224f, 0.44070982933044434f, 0.5626170039176941f,
    0.7229568362236023f, 1.0f};

__device__ __forceinline__ unsigned short f32_to_bf16_rne(float f) {
  union { float f; uint32_t u; } v;
  v.f = f;
  uint32_t lsb = (v.u >> 16) & 1u;
  v.u += 0x7fffu + lsb;
  return (unsigned short)(v.u >> 16);
}

// ---------------- Pass 1: NF4 dequant -> bf16 W [GN][GK] ----------------
__global__ void __launch_bounds__(256) dequant_nf4_kernel(
    const int* __restrict__ q, const float* __restrict__ scale,
    unsigned short* __restrict__ w) {
  __shared__ float lut[16];
  if (threadIdx.x < 16) lut[threadIdx.x] = NF4_LUT[threadIdx.x];
  __syncthreads();
  int t = blockIdx.x * 256 + threadIdx.x;
  const int4* q4 = reinterpret_cast<const int4*>(q);
  int4 c0 = q4[2 * t];
  int4 c1 = q4[2 * t + 1];
  float s = scale[t >> 3];
  int codes[8] = {c0.x, c0.y, c0.z, c0.w, c1.x, c1.y, c1.z, c1.w};
  union { unsigned short u[8]; int4 v; } r;
#pragma unroll
  for (int j = 0; j < 8; ++j)
    r.u[j] = f32_to_bf16_rne(lut[codes[j] & 15] * s);
  reinterpret_cast<int4*>(w)[t] = r.v;
}

// ---------------- Pass 2: x fp32 -> bf16 [GM][GK] ----------------
__global__ void __launch_bounds__(256) cvt_f32_bf16_kernel(
    const float* __restrict__ x, unsigned short* __restrict__ xb) {
  int t = blockIdx.x * 256 + threadIdx.x;
  const float4* x4 = reinterpret_cast<const float4*>(x);
  float4 a = x4[2 * t];
  float4 b = x4[2 * t + 1];
  union { unsigned short u[8]; int4 v; } r;
  r.u[0] = f32_to_bf16_rne(a.x); r.u[1] = f32_to_bf16_rne(a.y);
  r.u[2] = f32_to_bf16_rne(a.z); r.u[3] = f32_to_bf16_rne(a.w);
  r.u[4] = f32_to_bf16_rne(b.x); r.u[5] = f32_to_bf16_rne(b.y);
  r.u[6] = f32_to_bf16_rne(b.z); r.u[7] = f32_to_bf16_rne(b.w);
  reinterpret_cast<int4*>(xb)[t] = r.v;
}

// ------ Pass 3: 256x256 GEMM, BK=32, double-buffered, 2 blocks/CU ------
// 8 waves (2Mx4N), wave tile 128x64 (acc[8][4]). LDS = 2 x (A 16KB + B 16KB)
// = 64KB/block -> 2 co-resident blocks per CU provide the MFMA<->LDS/stage
// overlap (m114/m97 mechanism) instead of source-level pipelining.
// Simple T3-minimum loop: stage(next buf) -> 12 ds_read_b128 -> 32 MFMA ->
// __syncthreads (full drain; the stall is covered by the other block).
// Swizzle for 64B rows: granule g' = g ^ ((row>>1)&3); uniform 8 lanes/slot
// for both frag reads and linear global_load_lds writes (conflict-free).
#define AS1(p) ((const __attribute__((address_space(1))) void*)(p))
#define AS3(p) ((__attribute__((address_space(3))) void*)(p))

__global__ void __launch_bounds__(512, 4) gemm_dbuf_kernel(
    const unsigned short* __restrict__ A,  // [GM][GK] bf16 bits
    const unsigned short* __restrict__ B,  // [GN][GK] bf16 bits
    const float* __restrict__ bias, float* __restrict__ C) {
  constexpr int BK = 32, NT = GK / BK;  // 64 K-tiles
  __shared__ __align__(16) unsigned short As[2 * 256 * 32];  // 32 KB
  __shared__ __align__(16) unsigned short Bs[2 * 256 * 32];  // 32 KB

  int bid = blockIdx.x;                    // nwg = 512, %8==0 -> bijective
  int swz = (bid & 7) * 64 + (bid >> 3);
  int brow = (swz >> 5) * 256;             // 16 M-tiles
  int bcol = (swz & 31) * 256;             // 32 N-tiles

  int tid = threadIdx.x;
  int lane = tid & 63;
  int wave = tid >> 6;
  int wr = wave >> 2;   // 0..1 (M)
  int wc = wave & 3;    // 0..3 (N)
  int fr = lane & 15;
  int slot = lane >> 4;

  const unsigned short* Abase = A + (size_t)brow * GK;
  const unsigned short* Bbase = B + (size_t)bcol * GK;

  f32x4 acc[8][4] = {};

  // stage one 256x32 tile (16KB): 1024 chunks of 16B; thread t takes chunks
  // t and t+512. chunk c: row=c>>2, granule g=c&3; source granule is
  // inverse-swizzled g' = g ^ ((row>>1)&3); LDS dest stays linear (c*16).
  auto stage = [&](const unsigned short* gbase, unsigned short* lds, int buf,
                   int kt) {
#pragma unroll
    for (int i = 0; i < 2; ++i) {
      int c = tid + i * 512;
      int row = c >> 2;
      int gp = (c & 3) ^ ((row >> 1) & 3);
      __builtin_amdgcn_global_load_lds(
          AS1(gbase + (size_t)row * GK + kt + gp * 8),
          AS3((char*)lds + buf * 16384 + c * 16), 16, 0, 0);
    }
  };
  // read one bf16x8 fragment: row in tile, k-granule = slot (8 bf16 each);
  // stored swizzled at granule slot ^ ((row>>1)&3).
  auto ldf = [&](const unsigned short* lds, int buf, int row) -> bf16x8 {
    int off = buf * 16384 + row * 64 + ((slot ^ ((row >> 1) & 3)) << 4);
    return *reinterpret_cast<const bf16x8*>((const char*)lds + off);
  };

  stage(Abase, As, 0, 0);
  stage(Bbase, Bs, 0, 0);
  __syncthreads();

#pragma unroll 1
  for (int t = 0; t < NT; ++t) {
    int buf = t & 1;
    if (t + 1 < NT) {
      stage(Abase, As, buf ^ 1, (t + 1) * BK);
      stage(Bbase, Bs, buf ^ 1, (t + 1) * BK);
    }
    bf16x8 a[8], b[4];
#pragma unroll
    for (int m = 0; m < 8; ++m) a[m] = ldf(As, buf, wr * 128 + m * 16 + fr);
#pragma unroll
    for (int n = 0; n < 4; ++n) b[n] = ldf(Bs, buf, wc * 64 + n * 16 + fr);
    __builtin_amdgcn_s_setprio(1);
#pragma unroll
    for (int m = 0; m < 8; ++m)
#pragma unroll
      for (int n = 0; n < 4; ++n)
        acc[m][n] = __builtin_amdgcn_mfma_f32_16x16x32_bf16(
            a[m], b[n], acc[m][n], 0, 0, 0);
    __builtin_amdgcn_s_setprio(0);
    if (t + 1 < NT) __syncthreads();
  }

  // Epilogue: C/D frag layout col=fr, row=slot*4+reg [m89/m91]
  float bv[4];
#pragma unroll
  for (int n = 0; n < 4; ++n) bv[n] = bias[bcol + wc * 64 + n * 16 + fr];
#pragma unroll
  for (int m = 0; m < 8; ++m) {
    int grow0 = brow + wr * 128 + m * 16 + slot * 4;
#pragma unroll
    for (int n = 0; n < 4; ++n) {
      int gcol = bcol + wc * 64 + n * 16 + fr;
#pragma unroll
      for (int r = 0; r < 4; ++r)
        C[(size_t)(grow0 + r) * GN + gcol] = acc[m][n][r] + bv[n];
    }
  }
}

// ---------------- Fallback (ws too small): fp32, correct, slow ----------------
__global__ void __launch_bounds__(256) fallback_kernel(
    const float* __restrict__ x, const int* __restrict__ q,
    const float* __restrict__ scale, const float* __restrict__ bias,
    float* __restrict__ out) {
  __shared__ float wrow[GK];
  int n = blockIdx.x;
  for (int k = threadIdx.x; k < GK; k += 256) {
    size_t idx = (size_t)n * GK + k;
    wrow[k] = NF4_LUT[q[idx] & 15] * scale[idx >> 6];
  }
  __syncthreads();
  int m = blockIdx.y * 256 + threadIdx.x;
  const float* xr = x + (size_t)m * GK;
  float acc = 0.f;
  for (int k = 0; k < GK; ++k) acc += xr[k] * wrow[k];
  out[(size_t)m * GN + n] = acc + bias[n];
}

extern "C" void kernel_launch(void* const* d_in, const int* in_sizes, int n_in,
                              void* d_out, int out_size, void* d_ws, size_t ws_size,
                              hipStream_t stream) {
  const float* x = (const float*)d_in[0];
  const int* q = (const int*)d_in[1];
  const float* scale = (const float*)d_in[2];
  const float* bias = (const float*)d_in[3];
  float* out = (float*)d_out;

  const size_t wbytes = (size_t)GN * GK * 2;
  const size_t xbytes = (size_t)GM * GK * 2;

  if (ws_size >= wbytes + xbytes) {
    unsigned short* wq = (unsigned short*)d_ws;
    unsigned short* xb = (unsigned short*)((char*)d_ws + wbytes);
    dequant_nf4_kernel<<<(GN * GK / 8) / 256, 256, 0, stream>>>(q, scale, wq);
    cvt_f32_bf16_kernel<<<(GM * GK / 8) / 256, 256, 0, stream>>>(x, xb);
    gemm_dbuf_kernel<<<dim3((GM / 256) * (GN / 256)), 512, 0, stream>>>(
        xb, wq, bias, out);
  } else {
    fallback_kernel<<<dim3(GN, GM / 256), 256, 0, stream>>>(x, q, scale, bias, out);
  }
}

// Round 7
// 232.882 us; speedup vs baseline: 5.1911x; 5.1911x over previous
//
#include <hip/hip_runtime.h>
#include <stdint.h>

#define GM 4096   // 2*2048 rows of x
#define GN 8192   // out_features
#define GK 2048   // in_features

typedef float f32x4 __attribute__((ext_vector_type(4)));
typedef float f32x16 __attribute__((ext_vector_type(16)));
typedef __bf16 bf16x8 __attribute__((ext_vector_type(8)));

__device__ __constant__ float NF4_LUT[16] = {
    -1.0f, -0.6961928009986877f, -0.5250730514526367f, -0.39491748809814453f,
    -0.28444138169288635f, -0.18477343022823334f, -0.09105003625154495f, 0.0f,
    0.07958029955625534f, 0.16093020141124725f, 0.24611230194568634f,
    0.33791524171829224f, 0.44070982933044434f, 0.5626170039176941f,
    0.7229568362236023f, 1.0f};

__device__ __forceinline__ unsigned short f32_to_bf16_rne(float f) {
  union { float f; uint32_t u; } v;
  v.f = f;
  uint32_t lsb = (v.u >> 16) & 1u;
  v.u += 0x7fffu + lsb;
  return (unsigned short)(v.u >> 16);
}

// ---------------- Pass 1: NF4 dequant -> bf16 W [GN][GK] ----------------
__global__ void __launch_bounds__(256) dequant_nf4_kernel(
    const int* __restrict__ q, const float* __restrict__ scale,
    unsigned short* __restrict__ w) {
  __shared__ float lut[16];
  if (threadIdx.x < 16) lut[threadIdx.x] = NF4_LUT[threadIdx.x];
  __syncthreads();
  int t = blockIdx.x * 256 + threadIdx.x;
  const int4* q4 = reinterpret_cast<const int4*>(q);
  int4 c0 = q4[2 * t];
  int4 c1 = q4[2 * t + 1];
  float s = scale[t >> 3];
  int codes[8] = {c0.x, c0.y, c0.z, c0.w, c1.x, c1.y, c1.z, c1.w};
  union { unsigned short u[8]; int4 v; } r;
#pragma unroll
  for (int j = 0; j < 8; ++j)
    r.u[j] = f32_to_bf16_rne(lut[codes[j] & 15] * s);
  reinterpret_cast<int4*>(w)[t] = r.v;
}

// ---------------- Pass 2: x fp32 -> bf16 [GM][GK] ----------------
__global__ void __launch_bounds__(256) cvt_f32_bf16_kernel(
    const float* __restrict__ x, unsigned short* __restrict__ xb) {
  int t = blockIdx.x * 256 + threadIdx.x;
  const float4* x4 = reinterpret_cast<const float4*>(x);
  float4 a = x4[2 * t];
  float4 b = x4[2 * t + 1];
  union { unsigned short u[8]; int4 v; } r;
  r.u[0] = f32_to_bf16_rne(a.x); r.u[1] = f32_to_bf16_rne(a.y);
  r.u[2] = f32_to_bf16_rne(a.z); r.u[3] = f32_to_bf16_rne(a.w);
  r.u[4] = f32_to_bf16_rne(b.x); r.u[5] = f32_to_bf16_rne(b.y);
  r.u[6] = f32_to_bf16_rne(b.z); r.u[7] = f32_to_bf16_rne(b.w);
  reinterpret_cast<int4*>(xb)[t] = r.v;
}

// ------ Pass 3: persistent 256x256 GEMM, 32x32x16 MFMA, parity pipeline ----
// R3-structure (best: 1256 cyc/phase) with the MFMA shape swapped to
// 32x32x16 (2495 vs 2075 TF ceiling; half the MFMA issue slots). 8 waves
// (2Mx4N), BK=64, LDS 2x64KB static parity bufs. Frags: A-half = 2 mf x 4 ks
// (32 VGPR), B-half = 4 ks (16 VGPR), read 1+ phase ahead of consumption;
// quadrant snake Q1(a0b0) Q2(a1b0) Q3(a1b1) Q4(a0b1); stages of tile t+2 in
// P3/P4/P5 + B1(odd) in P1; VM6 at P4/P8. Swizzle: stored granule =
// logical ^ (row&7); read g = (ks*2+hl)^(lane&7) -> uniform 8 lanes/slot.
// C/D 32x32 layout: col=lane&31, row=(reg&3)+8*(reg>>2)+4*(lane>>5) [m74].
#define AS1(p) ((const __attribute__((address_space(1))) void*)(p))
#define AS3(p) ((__attribute__((address_space(3))) void*)(p))
#define VM6() asm volatile("s_waitcnt vmcnt(6)" ::: "memory")
#define FENCE() asm volatile("" ::: "memory")
#define BAR() do { FENCE(); __builtin_amdgcn_s_barrier(); FENCE(); } while (0)

__global__ void __launch_bounds__(512, 1) gemm_32x32_kernel(
    const unsigned short* __restrict__ A,  // [GM][GK] bf16 bits
    const unsigned short* __restrict__ B,  // [GN][GK] bf16 bits
    const float* __restrict__ bias, float* __restrict__ C) {
  constexpr int BK = 64;
  constexpr int NV = 64;  // 2 output tiles x 32 K-tiles
  __shared__ __align__(16) unsigned short As[2 * 256 * 64];  // 64 KB
  __shared__ __align__(16) unsigned short Bs[2 * 256 * 64];  // 64 KB

  int bid = blockIdx.x;                    // nwg = 256, bijective
  int swz = (bid & 7) * 32 + (bid >> 3);
  int brow = (swz & 15) * 256;             // A panel varies within XCD
  int pair = swz >> 4;                     // B pair-panel XCD-affine
  int bcol0 = pair * 512;

  int tid = threadIdx.x;
  int lane = tid & 63;
  int wave = tid >> 6;
  int wr = wave >> 2;   // 0..1 (M half of wave grid)
  int wc = wave & 3;    // 0..3 (N quarter)
  int l31 = lane & 31;
  int hl = lane >> 5;   // 0..1

  const unsigned short* Abase = A + (size_t)brow * GK;
  const unsigned short* Bbase0 = B + (size_t)bcol0 * GK;
  const unsigned short* Bbase1 = Bbase0 + (size_t)256 * GK;

  f32x16 acc[4][2] = {};
  // parity frag sets: a0/a1 = A half 0/1 (2 mf x 4 ks), b0/b1 = B half 0/1
  bf16x8 a0[2][2][4], a1[2][2][4], b0[2][4], b1[2][4];

  auto ldfrag = [&](const unsigned short* lds, int buf, int row,
                    int ks) -> bf16x8 {
    int g = ((ks << 1) | hl) ^ (lane & 7);
    int off = buf * 32768 + row * 128 + (g << 4);
    return *reinterpret_cast<const bf16x8*>((const char*)lds + off);
  };
  auto stage = [&](const unsigned short* gtile, unsigned short* lds, int buf,
                   int h, int kt) {
#pragma unroll
    for (int i = 0; i < 2; ++i) {
      int L = h * 16384 + i * 8192 + tid * 16;
      int s = L ^ (((L >> 7) & 7) << 4);
      __builtin_amdgcn_global_load_lds(
          AS1(gtile + (size_t)(s >> 7) * GK + kt + ((s & 127) >> 1)),
          AS3((char*)lds + buf * 32768 + L), 16, 0, 0);
    }
  };
  auto RD_A0 = [&](int p) {  // 8 reads, rows 0..127
#pragma unroll
    for (int mf = 0; mf < 2; ++mf)
#pragma unroll
      for (int ks = 0; ks < 4; ++ks)
        a0[p][mf][ks] = ldfrag(As, p, wr * 64 + mf * 32 + l31, ks);
  };
  auto RD_A1 = [&](int p) {  // 8 reads, rows 128..255
#pragma unroll
    for (int mf = 0; mf < 2; ++mf)
#pragma unroll
      for (int ks = 0; ks < 4; ++ks)
        a1[p][mf][ks] = ldfrag(As, p, 128 + wr * 64 + mf * 32 + l31, ks);
  };
  auto RD_B0 = [&](int p) {  // 4 reads
#pragma unroll
    for (int ks = 0; ks < 4; ++ks)
      b0[p][ks] = ldfrag(Bs, p, wc * 32 + l31, ks);
  };
  auto RD_B1 = [&](int p) {  // 4 reads
#pragma unroll
    for (int ks = 0; ks < 4; ++ks)
      b1[p][ks] = ldfrag(Bs, p, 128 + wc * 32 + l31, ks);
  };
  auto Q1 = [&](int p) {  // a0 x b0 -> acc[0..1][0]
    __builtin_amdgcn_s_setprio(1);
#pragma unroll
    for (int mf = 0; mf < 2; ++mf)
#pragma unroll
      for (int ks = 0; ks < 4; ++ks)
        acc[mf][0] = __builtin_amdgcn_mfma_f32_32x32x16_bf16(
            a0[p][mf][ks], b0[p][ks], acc[mf][0], 0, 0, 0);
    __builtin_amdgcn_s_setprio(0);
  };
  auto Q2 = [&](int p) {  // a1 x b0 -> acc[2..3][0]
    __builtin_amdgcn_s_setprio(1);
#pragma unroll
    for (int mf = 0; mf < 2; ++mf)
#pragma unroll
      for (int ks = 0; ks < 4; ++ks)
        acc[2 + mf][0] = __builtin_amdgcn_mfma_f32_32x32x16_bf16(
            a1[p][mf][ks], b0[p][ks], acc[2 + mf][0], 0, 0, 0);
    __builtin_amdgcn_s_setprio(0);
  };
  auto Q3 = [&](int p) {  // a1 x b1 -> acc[2..3][1]
    __builtin_amdgcn_s_setprio(1);
#pragma unroll
    for (int mf = 0; mf < 2; ++mf)
#pragma unroll
      for (int ks = 0; ks < 4; ++ks)
        acc[2 + mf][1] = __builtin_amdgcn_mfma_f32_32x32x16_bf16(
            a1[p][mf][ks], b1[p][ks], acc[2 + mf][1], 0, 0, 0);
    __builtin_amdgcn_s_setprio(0);
  };
  auto Q4 = [&](int p) {  // a0 x b1 -> acc[0..1][1]
    __builtin_amdgcn_s_setprio(1);
#pragma unroll
    for (int mf = 0; mf < 2; ++mf)
#pragma unroll
      for (int ks = 0; ks < 4; ++ks)
        acc[mf][1] = __builtin_amdgcn_mfma_f32_32x32x16_bf16(
            a0[p][mf][ks], b1[p][ks], acc[mf][1], 0, 0, 0);
    __builtin_amdgcn_s_setprio(0);
  };
  auto flush = [&](int bc) {
    float bv[2];
#pragma unroll
    for (int n = 0; n < 2; ++n) bv[n] = bias[bc + n * 128 + wc * 32 + l31];
#pragma unroll
    for (int m = 0; m < 4; ++m) {
      int grow = brow + (m >> 1) * 128 + wr * 64 + (m & 1) * 32 + 4 * hl;
#pragma unroll
      for (int n = 0; n < 2; ++n) {
        int gcol = bc + n * 128 + wc * 32 + l31;
#pragma unroll
        for (int reg = 0; reg < 16; ++reg) {
          int rif = (reg & 3) + 8 * (reg >> 2);
          C[(size_t)(grow + rif) * GN + gcol] = acc[m][n][reg] + bv[n];
        }
      }
    }
  };
  // one pipelined double-tile iteration over virtual tiles v=2j, 2j+1
  auto iter = [&](int j) {
    int t1 = 2 * j + 1;
    int t2 = 2 * j + 2; if (t2 > NV - 1) t2 = NV - 1;  // tail dummy restage
    int t3 = 2 * j + 3; if (t3 > NV - 1) t3 = NV - 1;
    const unsigned short* B1p = (t1 < 32) ? Bbase0 : Bbase1;
    const unsigned short* B2p = (t2 < 32) ? Bbase0 : Bbase1;
    const unsigned short* B3p = (t3 < 32) ? Bbase0 : Bbase1;
    int kt1 = (t1 & 31) * BK, kt2 = (t2 & 31) * BK, kt3 = (t3 & 31) * BK;
    // P1
    RD_A1(0);
    stage(B1p, Bs, 1, 1, kt1);
    BAR();
    Q1(0);
    // P2
    RD_B1(0);
    BAR();
    Q2(0);
    // P3
    stage(Abase, As, 0, 0, kt2);
    stage(B2p, Bs, 0, 0, kt2);
    BAR();
    Q3(0);
    // P4
    stage(Abase, As, 0, 1, kt2);
    VM6();
    BAR();
    RD_A0(1); RD_B0(1);
    Q4(0);
    // P5
    RD_A1(1);
    stage(B2p, Bs, 0, 1, kt2);
    BAR();
    Q1(1);
    // P6
    RD_B1(1);
    BAR();
    Q2(1);
    // P7
    stage(Abase, As, 1, 0, kt3);
    stage(B3p, Bs, 1, 0, kt3);
    BAR();
    Q3(1);
    // P8
    stage(Abase, As, 1, 1, kt3);
    VM6();
    BAR();
    RD_A0(0); RD_B0(0);
    Q4(1);
  };

  // Prologue: stage v0 fully + v1 {A0,B0,A1}
  stage(Abase, As, 0, 0, 0);
  stage(Bbase0, Bs, 0, 0, 0);
  stage(Abase, As, 0, 1, 0);
  stage(Bbase0, Bs, 0, 1, 0);
  stage(Abase, As, 1, 0, BK);
  stage(Bbase0, Bs, 1, 0, BK);
  stage(Abase, As, 1, 1, BK);
  VM6();
  BAR();
  RD_A0(0); RD_B0(0);

#pragma unroll 1
  for (int j = 0; j < 16; ++j) iter(j);

  // mid-flush: tile-1 stores drain under tile-2's K-loop
  flush(bcol0);
#pragma unroll
  for (int m = 0; m < 4; ++m)
#pragma unroll
    for (int n = 0; n < 2; ++n)
#pragma unroll
      for (int r = 0; r < 16; ++r) acc[m][n][r] = 0.f;

#pragma unroll 1
  for (int j = 16; j < 32; ++j) iter(j);

  flush(bcol0 + 256);
}

// ---------------- Fallback (ws too small): fp32, correct, slow ----------------
__global__ void __launch_bounds__(256) fallback_kernel(
    const float* __restrict__ x, const int* __restrict__ q,
    const float* __restrict__ scale, const float* __restrict__ bias,
    float* __restrict__ out) {
  __shared__ float wrow[GK];
  int n = blockIdx.x;
  for (int k = threadIdx.x; k < GK; k += 256) {
    size_t idx = (size_t)n * GK + k;
    wrow[k] = NF4_LUT[q[idx] & 15] * scale[idx >> 6];
  }
  __syncthreads();
  int m = blockIdx.y * 256 + threadIdx.x;
  const float* xr = x + (size_t)m * GK;
  float acc = 0.f;
  for (int k = 0; k < GK; ++k) acc += xr[k] * wrow[k];
  out[(size_t)m * GN + n] = acc + bias[n];
}

extern "C" void kernel_launch(void* const* d_in, const int* in_sizes, int n_in,
                              void* d_out, int out_size, void* d_ws, size_t ws_size,
                              hipStream_t stream) {
  const float* x = (const float*)d_in[0];
  const int* q = (const int*)d_in[1];
  const float* scale = (const float*)d_in[2];
  const float* bias = (const float*)d_in[3];
  float* out = (float*)d_out;

  const size_t wbytes = (size_t)GN * GK * 2;
  const size_t xbytes = (size_t)GM * GK * 2;

  if (ws_size >= wbytes + xbytes) {
    unsigned short* wq = (unsigned short*)d_ws;
    unsigned short* xb = (unsigned short*)((char*)d_ws + wbytes);
    dequant_nf4_kernel<<<(GN * GK / 8) / 256, 256, 0, stream>>>(q, scale, wq);
    cvt_f32_bf16_kernel<<<(GM * GK / 8) / 256, 256, 0, stream>>>(x, xb);
    gemm_32x32_kernel<<<dim3(256), 512, 0, stream>>>(xb, wq, bias, out);
  } else {
    fallback_kernel<<<dim3(GN, GM / 256), 256, 0, stream>>>(x, q, scale, bias, out);
  }
}

// Round 8
// 158.093 us; speedup vs baseline: 7.6469x; 1.4731x over previous
//
#include <hip/hip_runtime.h>
#include <stdint.h>

#define GM 4096   // 2*2048 rows of x
#define GN 8192   // out_features
#define GK 2048   // in_features

typedef float f32x4 __attribute__((ext_vector_type(4)));
typedef __bf16 bf16x8 __attribute__((ext_vector_type(8)));

__device__ __constant__ float NF4_LUT[16] = {
    -1.0f, -0.6961928009986877f, -0.5250730514526367f, -0.39491748809814453f,
    -0.28444138169288635f, -0.18477343022823334f, -0.09105003625154495f, 0.0f,
    0.07958029955625534f, 0.16093020141124725f, 0.24611230194568634f,
    0.33791524171829224f, 0.44070982933044434f, 0.5626170039176941f,
    0.7229568362236023f, 1.0f};

__device__ __forceinline__ unsigned short f32_to_bf16_rne(float f) {
  union { float f; uint32_t u; } v;
  v.f = f;
  uint32_t lsb = (v.u >> 16) & 1u;
  v.u += 0x7fffu + lsb;
  return (unsigned short)(v.u >> 16);
}

// ---------------- Pass 1: NF4 dequant -> bf16 W [GN][GK] ----------------
__global__ void __launch_bounds__(256) dequant_nf4_kernel(
    const int* __restrict__ q, const float* __restrict__ scale,
    unsigned short* __restrict__ w) {
  __shared__ float lut[16];
  if (threadIdx.x < 16) lut[threadIdx.x] = NF4_LUT[threadIdx.x];
  __syncthreads();
  int t = blockIdx.x * 256 + threadIdx.x;
  const int4* q4 = reinterpret_cast<const int4*>(q);
  int4 c0 = q4[2 * t];
  int4 c1 = q4[2 * t + 1];
  float s = scale[t >> 3];
  int codes[8] = {c0.x, c0.y, c0.z, c0.w, c1.x, c1.y, c1.z, c1.w};
  union { unsigned short u[8]; int4 v; } r;
#pragma unroll
  for (int j = 0; j < 8; ++j)
    r.u[j] = f32_to_bf16_rne(lut[codes[j] & 15] * s);
  reinterpret_cast<int4*>(w)[t] = r.v;
}

// ---------------- Pass 2: x fp32 -> bf16 [GM][GK] ----------------
__global__ void __launch_bounds__(256) cvt_f32_bf16_kernel(
    const float* __restrict__ x, unsigned short* __restrict__ xb) {
  int t = blockIdx.x * 256 + threadIdx.x;
  const float4* x4 = reinterpret_cast<const float4*>(x);
  float4 a = x4[2 * t];
  float4 b = x4[2 * t + 1];
  union { unsigned short u[8]; int4 v; } r;
  r.u[0] = f32_to_bf16_rne(a.x); r.u[1] = f32_to_bf16_rne(a.y);
  r.u[2] = f32_to_bf16_rne(a.z); r.u[3] = f32_to_bf16_rne(a.w);
  r.u[4] = f32_to_bf16_rne(b.x); r.u[5] = f32_to_bf16_rne(b.y);
  r.u[6] = f32_to_bf16_rne(b.z); r.u[7] = f32_to_bf16_rne(b.w);
  reinterpret_cast<int4*>(xb)[t] = r.v;
}

// ------ Pass 3: persistent 256x256 GEMM, m201-faithful 4-phase tile -------
// 8 waves (2Mx4N), BK=64, LDS 2x64KB parity bufs, 16x16x32 MFMA.
// Tile = 4 phases, each: [reads; stage; (LGKM8 if 12 reads); BAR; lgkm0
// (NO sched_barrier - reads are compiler-visible); setprio; 16 MFMA;
// setprio; BAR]. Snake reuses frags: phi1 reads a(qm0)+b0 (12), phi2 b1 (4),
// phi3 a(qm1) (8), phi4 none. Stages of tile t+2: phi2:A0+B0, phi3:B1,
// phi4:A1 (each region's read drained by its phase's lgkm0 before BAR-b,
// stage issued >=1 phase later => safe). Single VM(8) per tile at phi4
// (8 newest loads = this tile's 4 stage calls; everything older landed).
// Frag VGPR: a 32 + b0 16 + b1 16 + acc 128 ~= 222 (fits, no parity dup).
// Persistent 2 output tiles/block, XCD-affine B pairs, hidden mid-flush.
#define AS1(p) ((const __attribute__((address_space(1))) void*)(p))
#define AS3(p) ((__attribute__((address_space(3))) void*)(p))
#define VM8() asm volatile("s_waitcnt vmcnt(8)" ::: "memory")
#define LGKM8() asm volatile("s_waitcnt lgkmcnt(8)" ::: "memory")
#define LGKM0() asm volatile("s_waitcnt lgkmcnt(0)" ::: "memory")
#define FENCE() asm volatile("" ::: "memory")
#define BAR() do { FENCE(); __builtin_amdgcn_s_barrier(); FENCE(); } while (0)

__global__ void __launch_bounds__(512, 1) gemm_4phase_kernel(
    const unsigned short* __restrict__ A,  // [GM][GK] bf16 bits
    const unsigned short* __restrict__ B,  // [GN][GK] bf16 bits
    const float* __restrict__ bias, float* __restrict__ C) {
  constexpr int BK = 64;
  constexpr int NV = 64;  // 2 output tiles x 32 K-tiles
  __shared__ __align__(16) unsigned short As[2 * 256 * 64];  // 64 KB
  __shared__ __align__(16) unsigned short Bs[2 * 256 * 64];  // 64 KB

  int bid = blockIdx.x;                    // nwg = 256, bijective
  int swz = (bid & 7) * 32 + (bid >> 3);
  int brow = (swz & 15) * 256;             // A panel varies within XCD
  int pair = swz >> 4;                     // B pair-panel XCD-affine
  int bcol0 = pair * 512;

  int tid = threadIdx.x;
  int lane = tid & 63;
  int wave = tid >> 6;
  int wr = wave >> 2;   // 0..1
  int wc = wave & 3;    // 0..3
  int fr = lane & 15;
  int slot = lane >> 4;
  int swc = (slot << 4) ^ ((fr & 7) << 4);

  const unsigned short* Abase = A + (size_t)brow * GK;
  const unsigned short* Bbase0 = B + (size_t)bcol0 * GK;
  const unsigned short* Bbase1 = Bbase0 + (size_t)256 * GK;

  int arow = (wr * 64 + fr) * 128;
  int brw = (wc * 32 + fr) * 128;

  f32x4 acc[8][4] = {};
  bf16x8 a[4][2], b0[2][2], b1[2][2];   // 64 frag VGPR

  auto ldA = [&](int buf, int qm, int m, int kk) -> bf16x8 {
    int off = buf * 32768 + qm * 16384 + m * 2048 + arow + (swc ^ (kk << 6));
    return *reinterpret_cast<const bf16x8*>((const char*)As + off);
  };
  auto ldB = [&](int buf, int qn, int n, int kk) -> bf16x8 {
    int off = buf * 32768 + qn * 16384 + n * 2048 + brw + (swc ^ (kk << 6));
    return *reinterpret_cast<const bf16x8*>((const char*)Bs + off);
  };
  auto stage = [&](const unsigned short* gtile, unsigned short* lds, int buf,
                   int h, int kt) {
#pragma unroll
    for (int i = 0; i < 2; ++i) {
      int L = h * 16384 + i * 8192 + tid * 16;
      int s = L ^ (((L >> 7) & 7) << 4);
      __builtin_amdgcn_global_load_lds(
          AS1(gtile + (size_t)(s >> 7) * GK + kt + ((s & 127) >> 1)),
          AS3((char*)lds + buf * 32768 + L), 16, 0, 0);
    }
  };
  auto RD_A = [&](int buf, int qm) {
#pragma unroll
    for (int m = 0; m < 4; ++m)
#pragma unroll
      for (int kk = 0; kk < 2; ++kk) a[m][kk] = ldA(buf, qm, m, kk);
  };
  auto RD_B0 = [&](int buf) {
#pragma unroll
    for (int n = 0; n < 2; ++n)
#pragma unroll
      for (int kk = 0; kk < 2; ++kk) b0[n][kk] = ldB(buf, 0, n, kk);
  };
  auto RD_B1 = [&](int buf) {
#pragma unroll
    for (int n = 0; n < 2; ++n)
#pragma unroll
      for (int kk = 0; kk < 2; ++kk) b1[n][kk] = ldB(buf, 1, n, kk);
  };
  auto Q0 = [&](int mb) {  // a x b0 -> acc[mb..mb+3][0..1]
    __builtin_amdgcn_s_setprio(1);
#pragma unroll
    for (int m = 0; m < 4; ++m)
#pragma unroll
      for (int n = 0; n < 2; ++n)
#pragma unroll
        for (int kk = 0; kk < 2; ++kk)
          acc[mb + m][n] = __builtin_amdgcn_mfma_f32_16x16x32_bf16(
              a[m][kk], b0[n][kk], acc[mb + m][n], 0, 0, 0);
    __builtin_amdgcn_s_setprio(0);
  };
  auto Q1 = [&](int mb) {  // a x b1 -> acc[mb..mb+3][2..3]
    __builtin_amdgcn_s_setprio(1);
#pragma unroll
    for (int m = 0; m < 4; ++m)
#pragma unroll
      for (int n = 0; n < 2; ++n)
#pragma unroll
        for (int kk = 0; kk < 2; ++kk)
          acc[mb + m][2 + n] = __builtin_amdgcn_mfma_f32_16x16x32_bf16(
              a[m][kk], b1[n][kk], acc[mb + m][2 + n], 0, 0, 0);
    __builtin_amdgcn_s_setprio(0);
  };
  auto flush = [&](int bc) {
    float bv[4];
#pragma unroll
    for (int n = 0; n < 4; ++n)
      bv[n] = bias[bc + (n >> 1) * 128 + wc * 32 + (n & 1) * 16 + fr];
#pragma unroll
    for (int m = 0; m < 8; ++m) {
      int grow0 = brow + (m >> 2) * 128 + wr * 64 + (m & 3) * 16 + slot * 4;
#pragma unroll
      for (int n = 0; n < 4; ++n) {
        int gcol = bc + (n >> 1) * 128 + wc * 32 + (n & 1) * 16 + fr;
#pragma unroll
        for (int r = 0; r < 4; ++r)
          C[(size_t)(grow0 + r) * GN + gcol] = acc[m][n][r] + bv[n];
      }
    }
  };

  auto tile = [&](int v) {
    int buf = v & 1;
    int t2 = v + 2; if (t2 > NV - 1) t2 = NV - 1;  // tail dummy restage
    const unsigned short* B2p = (t2 < 32) ? Bbase0 : Bbase1;
    int kt2 = (t2 & 31) * BK;
    // phi1: 12 reads (a<-qm0, b0); no stage
    RD_A(buf, 0);
    RD_B0(buf);
    LGKM8();
    BAR();
    LGKM0();
    Q0(0);
    BAR();
    // phi2: 4 reads (b1); stage A0,B0 of t+2
    RD_B1(buf);
    stage(Abase, As, buf, 0, kt2);
    stage(B2p, Bs, buf, 0, kt2);
    BAR();
    LGKM0();
    Q1(0);
    BAR();
    // phi3: 8 reads (a<-qm1); stage B1 of t+2
    RD_A(buf, 1);
    stage(B2p, Bs, buf, 1, kt2);
    BAR();
    LGKM0();
    Q1(4);
    BAR();
    // phi4: 0 reads; stage A1 of t+2; single counted vmcnt per tile
    stage(Abase, As, buf, 1, kt2);
    VM8();
    BAR();
    Q0(4);
    BAR();
  };

  // Prologue: stage tiles 0 and 1 fully (16 loads); VM8 -> tile0 landed.
  stage(Abase, As, 0, 0, 0);
  stage(Bbase0, Bs, 0, 0, 0);
  stage(Bbase0, Bs, 0, 1, 0);
  stage(Abase, As, 0, 1, 0);
  stage(Abase, As, 1, 0, BK);
  stage(Bbase0, Bs, 1, 0, BK);
  stage(Bbase0, Bs, 1, 1, BK);
  stage(Abase, As, 1, 1, BK);
  VM8();
  BAR();

#pragma unroll 1
  for (int v = 0; v < 32; ++v) tile(v);

  flush(bcol0);  // stores drain under the 2nd K-loop
#pragma unroll
  for (int m = 0; m < 8; ++m)
#pragma unroll
    for (int n = 0; n < 4; ++n)
      acc[m][n] = f32x4{0.f, 0.f, 0.f, 0.f};

#pragma unroll 1
  for (int v = 32; v < 64; ++v) tile(v);

  flush(bcol0 + 256);
}

// ---------------- Fallback (ws too small): fp32, correct, slow ----------------
__global__ void __launch_bounds__(256) fallback_kernel(
    const float* __restrict__ x, const int* __restrict__ q,
    const float* __restrict__ scale, const float* __restrict__ bias,
    float* __restrict__ out) {
  __shared__ float wrow[GK];
  int n = blockIdx.x;
  for (int k = threadIdx.x; k < GK; k += 256) {
    size_t idx = (size_t)n * GK + k;
    wrow[k] = NF4_LUT[q[idx] & 15] * scale[idx >> 6];
  }
  __syncthreads();
  int m = blockIdx.y * 256 + threadIdx.x;
  const float* xr = x + (size_t)m * GK;
  float acc = 0.f;
  for (int k = 0; k < GK; ++k) acc += xr[k] * wrow[k];
  out[(size_t)m * GN + n] = acc + bias[n];
}

extern "C" void kernel_launch(void* const* d_in, const int* in_sizes, int n_in,
                              void* d_out, int out_size, void* d_ws, size_t ws_size,
                              hipStream_t stream) {
  const float* x = (const float*)d_in[0];
  const int* q = (const int*)d_in[1];
  const float* scale = (const float*)d_in[2];
  const float* bias = (const float*)d_in[3];
  float* out = (float*)d_out;

  const size_t wbytes = (size_t)GN * GK * 2;
  const size_t xbytes = (size_t)GM * GK * 2;

  if (ws_size >= wbytes + xbytes) {
    unsigned short* wq = (unsigned short*)d_ws;
    unsigned short* xb = (unsigned short*)((char*)d_ws + wbytes);
    dequant_nf4_kernel<<<(GN * GK / 8) / 256, 256, 0, stream>>>(q, scale, wq);
    cvt_f32_bf16_kernel<<<(GM * GK / 8) / 256, 256, 0, stream>>>(x, xb);
    gemm_4phase_kernel<<<dim3(256), 512, 0, stream>>>(xb, wq, bias, out);
  } else {
    fallback_kernel<<<dim3(GN, GM / 256), 256, 0, stream>>>(x, q, scale, bias, out);
  }
}

// Round 10
// 151.520 us; speedup vs baseline: 7.9786x; 1.0434x over previous
//
#include <hip/hip_runtime.h>
#include <stdint.h>

#define GM 4096   // 2*2048 rows of x
#define GN 8192   // out_features
#define GK 2048   // in_features

typedef float f32x4 __attribute__((ext_vector_type(4)));
typedef __bf16 bf16x8 __attribute__((ext_vector_type(8)));

__device__ __constant__ float NF4_LUT[16] = {
    -1.0f, -0.6961928009986877f, -0.5250730514526367f, -0.39491748809814453f,
    -0.28444138169288635f, -0.18477343022823334f, -0.09105003625154495f, 0.0f,
    0.07958029955625534f, 0.16093020141124725f, 0.24611230194568634f,
    0.33791524171829224f, 0.44070982933044434f, 0.5626170039176941f,
    0.7229568362236023f, 1.0f};

__device__ __forceinline__ unsigned short f32_to_bf16_rne(float f) {
  union { float f; uint32_t u; } v;
  v.f = f;
  uint32_t lsb = (v.u >> 16) & 1u;
  v.u += 0x7fffu + lsb;
  return (unsigned short)(v.u >> 16);
}

// ---- Pass 1 (merged): NF4 dequant -> bf16 W  AND  x fp32 -> bf16 ----
// W: GN*GK/8 threads = 8192 blocks. x: GM*GK/8 threads = 4096 blocks.
// blocks [0,8192): dequant (8 codes/thread); [8192,12288): cvt (8 floats).
__global__ void __launch_bounds__(256) prep_kernel(
    const int* __restrict__ q, const float* __restrict__ scale,
    unsigned short* __restrict__ w, const float* __restrict__ x,
    unsigned short* __restrict__ xb) {
  int b = blockIdx.x;
  if (b < 8192) {
    __shared__ float lut[16];
    if (threadIdx.x < 16) lut[threadIdx.x] = NF4_LUT[threadIdx.x];
    __syncthreads();
    int t = b * 256 + threadIdx.x;
    const int4* q4 = reinterpret_cast<const int4*>(q);
    int4 c0 = q4[2 * t];
    int4 c1 = q4[2 * t + 1];
    float s = scale[t >> 3];
    int codes[8] = {c0.x, c0.y, c0.z, c0.w, c1.x, c1.y, c1.z, c1.w};
    union { unsigned short u[8]; int4 v; } r;
#pragma unroll
    for (int j = 0; j < 8; ++j)
      r.u[j] = f32_to_bf16_rne(lut[codes[j] & 15] * s);
    reinterpret_cast<int4*>(w)[t] = r.v;
  } else {
    int t = (b - 8192) * 256 + threadIdx.x;
    const float4* x4 = reinterpret_cast<const float4*>(x);
    float4 a = x4[2 * t];
    float4 bb = x4[2 * t + 1];
    union { unsigned short u[8]; int4 v; } r;
    r.u[0] = f32_to_bf16_rne(a.x);  r.u[1] = f32_to_bf16_rne(a.y);
    r.u[2] = f32_to_bf16_rne(a.z);  r.u[3] = f32_to_bf16_rne(a.w);
    r.u[4] = f32_to_bf16_rne(bb.x); r.u[5] = f32_to_bf16_rne(bb.y);
    r.u[6] = f32_to_bf16_rne(bb.z); r.u[7] = f32_to_bf16_rne(bb.w);
    reinterpret_cast<int4*>(xb)[t] = r.v;
  }
}

// ------ Pass 2: persistent 256x256 GEMM (best-measured R4 variant) ------
// 8 waves (2Mx4N), BK=64, 16x16x32 MFMA, LDS 2x64KB static parity bufs.
// Frag ds_reads issued ONE PHASE ahead of their MFMA (compiler emits counted
// lgkmcnt). Snake quadrants; stages P1:B1(O), P3:A0+B0(E+2), P4:A1(E+2),
// P5:B1(E+2), P7:A0+B0(O+2), P8:A1(O+2); vmcnt(6) at P4/P8 only.
// T2 swizzle byte ^= ((row&7)<<4) via pre-swizzled global src (0 conflicts).
// Persistent: 2 output tiles/block (brow fixed, bcol pair), seamless stage
// stream across boundary, tile-1 flush drains under tile-2's K-loop.
// XCD-affine B pair-panels: FETCH ~156MB (B ~1.2x, A ~8x from L2/L3).
#define AS1(p) ((const __attribute__((address_space(1))) void*)(p))
#define AS3(p) ((__attribute__((address_space(3))) void*)(p))
#define VM6() asm volatile("s_waitcnt vmcnt(6)" ::: "memory")
#define FENCE() asm volatile("" ::: "memory")
#define BAR() do { FENCE(); __builtin_amdgcn_s_barrier(); FENCE(); } while (0)

__global__ void __launch_bounds__(512, 1) gemm_8phase_kernel(
    const unsigned short* __restrict__ A,  // [GM][GK] bf16 bits
    const unsigned short* __restrict__ B,  // [GN][GK] bf16 bits
    const float* __restrict__ bias, float* __restrict__ C) {
  constexpr int BK = 64;
  constexpr int NV = 64;  // virtual K-tiles: 2 output tiles x 32
  __shared__ __align__(16) unsigned short As[2 * 256 * 64];  // 64 KB
  __shared__ __align__(16) unsigned short Bs[2 * 256 * 64];  // 64 KB

  int bid = blockIdx.x;                    // nwg = 256, %8==0 -> bijective
  int swz = (bid & 7) * 32 + (bid >> 3);
  int brow = (swz & 15) * 256;             // A panel varies within XCD
  int pair = swz >> 4;                     // B pair-panel is XCD-affine
  int bcol0 = pair * 512;

  int tid = threadIdx.x;
  int lane = tid & 63;
  int wave = tid >> 6;
  int wr = wave >> 2;   // 0..1
  int wc = wave & 3;    // 0..3
  int fr = lane & 15;
  int slot = lane >> 4;
  int swc = (slot << 4) ^ ((fr & 7) << 4);

  const unsigned short* Abase = A + (size_t)brow * GK;
  const unsigned short* Bbase0 = B + (size_t)bcol0 * GK;
  const unsigned short* Bbase1 = Bbase0 + (size_t)256 * GK;

  int arow = (wr * 64 + fr) * 128;
  int brw = (wc * 32 + fr) * 128;

  f32x4 acc[8][4] = {};
  bf16x8 a0[2][4][2], a1[2][4][2], b0[2][2][2], b1[2][2][2];

  auto ldA = [&](int buf, int qm, int m, int kk) -> bf16x8 {
    int off = buf * 32768 + qm * 16384 + m * 2048 + arow + (swc ^ (kk << 6));
    return *reinterpret_cast<const bf16x8*>((const char*)As + off);
  };
  auto ldB = [&](int buf, int qn, int n, int kk) -> bf16x8 {
    int off = buf * 32768 + qn * 16384 + n * 2048 + brw + (swc ^ (kk << 6));
    return *reinterpret_cast<const bf16x8*>((const char*)Bs + off);
  };
  auto stage = [&](const unsigned short* gtile, unsigned short* lds, int buf,
                   int h, int kt) {
#pragma unroll
    for (int i = 0; i < 2; ++i) {
      int L = h * 16384 + i * 8192 + tid * 16;
      int s = L ^ (((L >> 7) & 7) << 4);
      __builtin_amdgcn_global_load_lds(
          AS1(gtile + (size_t)(s >> 7) * GK + kt + ((s & 127) >> 1)),
          AS3((char*)lds + buf * 32768 + L), 16, 0, 0);
    }
  };
  auto RD_A1 = [&](int p) {
#pragma unroll
    for (int m = 0; m < 4; ++m)
#pragma unroll
      for (int kk = 0; kk < 2; ++kk) a1[p][m][kk] = ldA(p, 1, m, kk);
  };
  auto RD_B1 = [&](int p) {
#pragma unroll
    for (int n = 0; n < 2; ++n)
#pragma unroll
      for (int kk = 0; kk < 2; ++kk) b1[p][n][kk] = ldB(p, 1, n, kk);
  };
  auto RD_A0B0 = [&](int p) {
#pragma unroll
    for (int m = 0; m < 4; ++m)
#pragma unroll
      for (int kk = 0; kk < 2; ++kk) a0[p][m][kk] = ldA(p, 0, m, kk);
#pragma unroll
    for (int n = 0; n < 2; ++n)
#pragma unroll
      for (int kk = 0; kk < 2; ++kk) b0[p][n][kk] = ldB(p, 0, n, kk);
  };
  auto Q1 = [&](int p) {
    __builtin_amdgcn_s_setprio(1);
#pragma unroll
    for (int m = 0; m < 4; ++m)
#pragma unroll
      for (int n = 0; n < 2; ++n)
#pragma unroll
        for (int kk = 0; kk < 2; ++kk)
          acc[m][n] = __builtin_amdgcn_mfma_f32_16x16x32_bf16(
              a0[p][m][kk], b0[p][n][kk], acc[m][n], 0, 0, 0);
    __builtin_amdgcn_s_setprio(0);
  };
  auto Q2 = [&](int p) {
    __builtin_amdgcn_s_setprio(1);
#pragma unroll
    for (int m = 0; m < 4; ++m)
#pragma unroll
      for (int n = 0; n < 2; ++n)
#pragma unroll
        for (int kk = 0; kk < 2; ++kk)
          acc[4 + m][n] = __builtin_amdgcn_mfma_f32_16x16x32_bf16(
              a1[p][m][kk], b0[p][n][kk], acc[4 + m][n], 0, 0, 0);
    __builtin_amdgcn_s_setprio(0);
  };
  auto Q3 = [&](int p) {
    __builtin_amdgcn_s_setprio(1);
#pragma unroll
    for (int m = 0; m < 4; ++m)
#pragma unroll
      for (int n = 0; n < 2; ++n)
#pragma unroll
        for (int kk = 0; kk < 2; ++kk)
          acc[4 + m][2 + n] = __builtin_amdgcn_mfma_f32_16x16x32_bf16(
              a1[p][m][kk], b1[p][n][kk], acc[4 + m][2 + n], 0, 0, 0);
    __builtin_amdgcn_s_setprio(0);
  };
  auto Q4 = [&](int p) {
    __builtin_amdgcn_s_setprio(1);
#pragma unroll
    for (int m = 0; m < 4; ++m)
#pragma unroll
      for (int n = 0; n < 2; ++n)
#pragma unroll
        for (int kk = 0; kk < 2; ++kk)
          acc[m][2 + n] = __builtin_amdgcn_mfma_f32_16x16x32_bf16(
              a0[p][m][kk], b1[p][n][kk], acc[m][2 + n], 0, 0, 0);
    __builtin_amdgcn_s_setprio(0);
  };
  auto flush = [&](int bc) {
    float bv[4];
#pragma unroll
    for (int n = 0; n < 4; ++n)
      bv[n] = bias[bc + (n >> 1) * 128 + wc * 32 + (n & 1) * 16 + fr];
#pragma unroll
    for (int m = 0; m < 8; ++m) {
      int grow0 = brow + (m >> 2) * 128 + wr * 64 + (m & 3) * 16 + slot * 4;
#pragma unroll
      for (int n = 0; n < 4; ++n) {
        int gcol = bc + (n >> 1) * 128 + wc * 32 + (n & 1) * 16 + fr;
#pragma unroll
        for (int r = 0; r < 4; ++r)
          C[(size_t)(grow0 + r) * GN + gcol] = acc[m][n][r] + bv[n];
      }
    }
  };
  auto iter = [&](int j) {
    int t1 = 2 * j + 1;
    int t2 = 2 * j + 2; if (t2 > NV - 1) t2 = NV - 1;  // tail dummy restage
    int t3 = 2 * j + 3; if (t3 > NV - 1) t3 = NV - 1;
    const unsigned short* B1p = (t1 < 32) ? Bbase0 : Bbase1;
    const unsigned short* B2p = (t2 < 32) ? Bbase0 : Bbase1;
    const unsigned short* B3p = (t3 < 32) ? Bbase0 : Bbase1;
    int kt1 = (t1 & 31) * BK, kt2 = (t2 & 31) * BK, kt3 = (t3 & 31) * BK;
    // P1
    RD_A1(0);
    stage(B1p, Bs, 1, 1, kt1);
    BAR();
    Q1(0);
    // P2
    RD_B1(0);
    BAR();
    Q2(0);
    // P3
    stage(Abase, As, 0, 0, kt2);
    stage(B2p, Bs, 0, 0, kt2);
    BAR();
    Q3(0);
    // P4
    stage(Abase, As, 0, 1, kt2);
    VM6();
    BAR();
    RD_A0B0(1);
    Q4(0);
    // P5
    RD_A1(1);
    stage(B2p, Bs, 0, 1, kt2);
    BAR();
    Q1(1);
    // P6
    RD_B1(1);
    BAR();
    Q2(1);
    // P7
    stage(Abase, As, 1, 0, kt3);
    stage(B3p, Bs, 1, 0, kt3);
    BAR();
    Q3(1);
    // P8
    stage(Abase, As, 1, 1, kt3);
    VM6();
    BAR();
    RD_A0B0(0);
    Q4(1);
  };

  // Prologue: stage v0 fully + v1 {A0,B0,A1}
  stage(Abase, As, 0, 0, 0);
  stage(Bbase0, Bs, 0, 0, 0);
  stage(Abase, As, 0, 1, 0);
  stage(Bbase0, Bs, 0, 1, 0);
  stage(Abase, As, 1, 0, BK);
  stage(Bbase0, Bs, 1, 0, BK);
  stage(Abase, As, 1, 1, BK);
  VM6();
  BAR();
  RD_A0B0(0);

#pragma unroll 1
  for (int j = 0; j < 16; ++j) iter(j);

  // mid-flush: tile-1 stores fly while tile-2's K-loop runs
  flush(bcol0);
#pragma unroll
  for (int m = 0; m < 8; ++m)
#pragma unroll
    for (int n = 0; n < 4; ++n)
      acc[m][n] = f32x4{0.f, 0.f, 0.f, 0.f};

#pragma unroll 1
  for (int j = 16; j < 32; ++j) iter(j);

  flush(bcol0 + 256);
}

// ---------------- Fallback (ws too small): fp32, correct, slow ----------------
__global__ void __launch_bounds__(256) fallback_kernel(
    const float* __restrict__ x, const int* __restrict__ q,
    const float* __restrict__ scale, const float* __restrict__ bias,
    float* __restrict__ out) {
  __shared__ float wrow[GK];
  int n = blockIdx.x;
  for (int k = threadIdx.x; k < GK; k += 256) {
    size_t idx = (size_t)n * GK + k;
    wrow[k] = NF4_LUT[q[idx] & 15] * scale[idx >> 6];
  }
  __syncthreads();
  int m = blockIdx.y * 256 + threadIdx.x;
  const float* xr = x + (size_t)m * GK;
  float acc = 0.f;
  for (int k = 0; k < GK; ++k) acc += xr[k] * wrow[k];
  out[(size_t)m * GN + n] = acc + bias[n];
}

extern "C" void kernel_launch(void* const* d_in, const int* in_sizes, int n_in,
                              void* d_out, int out_size, void* d_ws, size_t ws_size,
                              hipStream_t stream) {
  const float* x = (const float*)d_in[0];
  const int* q = (const int*)d_in[1];
  const float* scale = (const float*)d_in[2];
  const float* bias = (const float*)d_in[3];
  float* out = (float*)d_out;

  const size_t wbytes = (size_t)GN * GK * 2;
  const size_t xbytes = (size_t)GM * GK * 2;

  if (ws_size >= wbytes + xbytes) {
    unsigned short* wq = (unsigned short*)d_ws;
    unsigned short* xb = (unsigned short*)((char*)d_ws + wbytes);
    prep_kernel<<<dim3(8192 + 4096), 256, 0, stream>>>(q, scale, wq, x, xb);
    gemm_8phase_kernel<<<dim3(256), 512, 0, stream>>>(xb, wq, bias, out);
  } else {
    fallback_kernel<<<dim3(GN, GM / 256), 256, 0, stream>>>(x, q, scale, bias, out);
  }
}